// Round 15
// baseline (103.013 us; speedup 1.0000x reference)
//
#include <hip/hip_runtime.h>

// ---------------------------------------------------------------------------
// Zero-coordination region-local sort + scattered-run gather reduction.
//   build (1 block = 1 tile of 2048 atoms): LDS hist over 391 buckets ->
//     hierarchical scan -> stage bucket-sorted in LDS -> LINEAR write-out to
//     own payload region (fully coalesced; region is block-private) + one
//     coalesced offset row off[t][0..nb]. No global hist/scan/cursors.
//   reduce (1 block = 1 bucket of 512 frags): load 977 tile descriptors ->
//     scan lens -> cum/T; per 1024-atom tile: binary-search cum per lane,
//     ONE parallel payload load per lane (runs ~5.2 atoms, partially
//     coalesced), int ds_add_rtn rank -> scan -> LDS fragment-sorted stage ->
//     thread t (=frag t) accumulates 13 register moments -> double Cramer.
// Rationale: r13's GLOBAL scatter pinned at ~2.2 TB/s (55us) across 3 levers;
//   r5 showed region-local scatter is cheaper (private L2-resident dst); the
//   scattered-READ cost was never measured clean (r6 had the ds_add_f32 bug).
// Fallback (ws too small / nb>512 / tiles>1024): round-1 atomics.
// ---------------------------------------------------------------------------

#define BSHIFT 9
#define BFRAGS (1 << BSHIFT)     // 512 fragments per bucket
#define NBMAX  512
#define NACC   13

#define B_THREADS 1024
#define TILE_B    2048           // atoms per build block; stage = 64 KB
#define NT_B      2
#define R_THREADS 512
#define TILE      1024           // reduce tile; stage = 32 KB
#define NT_R      2
#define MAXTILES  1024

// ---------------- fallback path (round-1, known correct) -------------------
__global__ void atom_accum_kernel(const float* __restrict__ f_atom,
                                  const float* __restrict__ atom_pos,
                                  const float* __restrict__ T_frag,
                                  const int*   __restrict__ frag_id,
                                  float* __restrict__ acc,
                                  int n_atom, int n_frag) {
    int i = blockIdx.x * blockDim.x + threadIdx.x;
    if (i >= n_atom) return;
    float fx = f_atom[3 * i + 0], fy = f_atom[3 * i + 1], fz = f_atom[3 * i + 2];
    float px = atom_pos[3 * i + 0], py = atom_pos[3 * i + 1], pz = atom_pos[3 * i + 2];
    int fid = frag_id[i];
    float rx = px - T_frag[3 * fid + 0];
    float ry = py - T_frag[3 * fid + 1];
    float rz = pz - T_frag[3 * fid + 2];
    atomicAdd(&acc[0 * n_frag + fid], 1.0f);
    atomicAdd(&acc[1 * n_frag + fid], fx);
    atomicAdd(&acc[2 * n_frag + fid], fy);
    atomicAdd(&acc[3 * n_frag + fid], fz);
    atomicAdd(&acc[4 * n_frag + fid], ry * fz - rz * fy);
    atomicAdd(&acc[5 * n_frag + fid], rz * fx - rx * fz);
    atomicAdd(&acc[6 * n_frag + fid], rx * fy - ry * fx);
    atomicAdd(&acc[7 * n_frag + fid], rx * rx);
    atomicAdd(&acc[8 * n_frag + fid], ry * ry);
    atomicAdd(&acc[9 * n_frag + fid], rz * rz);
    atomicAdd(&acc[10 * n_frag + fid], rx * ry);
    atomicAdd(&acc[11 * n_frag + fid], rx * rz);
    atomicAdd(&acc[12 * n_frag + fid], ry * rz);
}

__device__ __forceinline__ void solve_frag(const float s[NACC], int fs,
                                           float* vout, float* oout) {
    float inv_cnt = 1.0f / fmaxf(s[0], 1.0f);
    vout[0] = s[1] * inv_cnt;
    vout[1] = s[2] * inv_cnt;
    vout[2] = s[3] * inv_cnt;

    double sxx = (double)s[7], syy = (double)s[8], szz = (double)s[9];
    double sxy = (double)s[10], sxz = (double)s[11], syz = (double)s[12];
    const double eps = 1e-4;
    double d = sxx + syy + szz;
    double a00 = d - sxx + eps, a11 = d - syy + eps, a22 = d - szz + eps;
    double a01 = -sxy, a02 = -sxz, a12 = -syz;

    double c00 = a11 * a22 - a12 * a12;
    double c01 = a02 * a12 - a01 * a22;
    double c02 = a01 * a12 - a02 * a11;
    double det = a00 * c00 + a01 * c01 + a02 * c02;
    double inv_det = (det != 0.0) ? 1.0 / det : 0.0;
    double c11 = a00 * a22 - a02 * a02;
    double c12 = a01 * a02 - a00 * a12;
    double c22 = a00 * a11 - a01 * a01;

    double tx = (double)s[4], ty = (double)s[5], tz = (double)s[6];
    if (fs <= 1) {
        oout[0] = 0.0f; oout[1] = 0.0f; oout[2] = 0.0f;
    } else {
        oout[0] = (float)((c00 * tx + c01 * ty + c02 * tz) * inv_det);
        oout[1] = (float)((c01 * tx + c11 * ty + c12 * tz) * inv_det);
        oout[2] = (float)((c02 * tx + c12 * ty + c22 * tz) * inv_det);
    }
}

__global__ void finalize_accum_kernel(const float* __restrict__ acc,
                                      const int* __restrict__ frag_sizes,
                                      float* __restrict__ out, int n_frag) {
    int i = blockIdx.x * blockDim.x + threadIdx.x;
    if (i >= n_frag) return;
    float s[NACC];
#pragma unroll
    for (int c = 0; c < NACC; ++c) s[c] = acc[(size_t)c * n_frag + i];
    float v[3], o[3];
    solve_frag(s, frag_sizes[i], v, o);
    out[3 * i + 0] = v[0]; out[3 * i + 1] = v[1]; out[3 * i + 2] = v[2];
    float* om = out + 3 * (size_t)n_frag;
    om[3 * i + 0] = o[0]; om[3 * i + 1] = o[1]; om[3 * i + 2] = o[2];
}

// ---------------- sorted path ----------------------------------------------

__global__ __launch_bounds__(B_THREADS)
void build_kernel(const float* __restrict__ f_atom,
                  const float* __restrict__ atom_pos,
                  const float* __restrict__ T_frag,
                  const int* __restrict__ frag_id,
                  unsigned* __restrict__ off,      // [ntiles][nb+1]
                  float* __restrict__ payload,
                  int n_atom, int nb) {
    __shared__ float stage[TILE_B * 8];        // 64 KB bucket-sorted tile
    __shared__ unsigned cnt[NBMAX];
    __shared__ unsigned tfs[NBMAX];
    __shared__ unsigned wsum[B_THREADS / 64];

    int tid = threadIdx.x;
    int wave = tid >> 6, lane = tid & 63;
    int blk = blockIdx.x;
    int c0 = blk * TILE_B;
    int cend = min(c0 + TILE_B, n_atom);
    int tcount = cend - c0;

    if (tid < NBMAX) cnt[tid] = 0;
    __syncthreads();                                        // B1

    // load + rank (one int ds_add_rtn per atom)
    float4 p0j[NT_B], p1j[NT_B];
    unsigned rankj[NT_B]; int bj[NT_B]; bool actj[NT_B];
#pragma unroll
    for (int j = 0; j < NT_B; ++j) {
        int i = c0 + tid + j * B_THREADS;
        actj[j] = (i < cend);
        bj[j] = 0; rankj[j] = 0;
        if (actj[j]) {
            int fid = frag_id[i];
            int b = fid >> BSHIFT;
            bj[j] = b;
            rankj[j] = atomicAdd(&cnt[b], 1u);
            float fx = f_atom[3 * i + 0], fy = f_atom[3 * i + 1],
                  fz = f_atom[3 * i + 2];
            float rx = atom_pos[3 * i + 0] - T_frag[3 * fid + 0];
            float ry = atom_pos[3 * i + 1] - T_frag[3 * fid + 1];
            float rz = atom_pos[3 * i + 2] - T_frag[3 * fid + 2];
            p0j[j] = make_float4(fx, fy, fz, __int_as_float(fid));
            p1j[j] = make_float4(rx, ry, rz, 0.0f);
        }
    }
    __syncthreads();                                        // B2

    // barrier-uniform hierarchical exclusive scan of cnt[0..NBMAX)
    unsigned v = (tid < NBMAX) ? cnt[tid] : 0u;
    unsigned incl = v;
#pragma unroll
    for (int o = 1; o < 64; o <<= 1) {
        unsigned x = __shfl_up(incl, o);
        if (lane >= o) incl += x;
    }
    if (lane == 63) wsum[wave] = incl;
    __syncthreads();                                        // S1
    unsigned wbase = 0;
#pragma unroll
    for (int w = 0; w < B_THREADS / 64; ++w)
        wbase += (w < wave) ? wsum[w] : 0u;
    unsigned excl = wbase + incl - v;
    if (tid < NBMAX) tfs[tid] = excl;

    // offset row (coalesced): tile-local exclusive starts + total
    size_t row = (size_t)blk * (nb + 1);
    if (tid < nb) off[row + tid] = excl;
    if (tid == B_THREADS - 1) off[row + nb] = wbase + incl;  // == tcount
    __syncthreads();                                        // S2

    // stage bucket-sorted
#pragma unroll
    for (int j = 0; j < NT_B; ++j) {
        if (actj[j]) {
            unsigned slot = tfs[bj[j]] + rankj[j];
            float4* d = (float4*)&stage[(size_t)slot * 8];
            d[0] = p0j[j];
            d[1] = p1j[j];
        }
    }
    __syncthreads();                                        // B3

    // linear write-out: fully coalesced, region = own slot range
    for (int s = tid; s < tcount; s += B_THREADS) {
        const float4* q = (const float4*)&stage[(size_t)s * 8];
        float4* p = (float4*)(payload + ((size_t)c0 + s) * 8);
        p[0] = q[0];
        p[1] = q[1];
    }
}

__global__ __launch_bounds__(R_THREADS)
void reduce_kernel(const float* __restrict__ payload,
                   const unsigned* __restrict__ off,
                   const int* __restrict__ frag_sizes,
                   float* __restrict__ out,
                   int n_frag, int nb, int ntiles) {
    __shared__ float stage[TILE * 8];          // 32 KB fragment-sorted tile
    __shared__ unsigned o0s[MAXTILES];         // per-tile run start
    __shared__ unsigned cum[MAXTILES + 1];     // exclusive scan of run lens
    __shared__ unsigned cnt[BFRAGS];
    __shared__ unsigned fstart[BFRAGS + 1];
    __shared__ unsigned wsum[R_THREADS / 64];

    int b = blockIdx.x;
    int tid = threadIdx.x;                     // thread t owns frag t
    int wave = tid >> 6, lane = tid & 63;
    int W = nb + 1;

    // ---- descriptors: 2 tiles per thread, then paired scan of lens
    int k0 = 2 * tid, k1 = 2 * tid + 1;
    unsigned l0 = 0, l1 = 0;
    if (k0 < ntiles) {
        size_t r = (size_t)k0 * W;
        unsigned a = off[r + b];
        o0s[k0] = a;
        l0 = off[r + b + 1] - a;
    }
    if (k1 < ntiles) {
        size_t r = (size_t)k1 * W;
        unsigned a = off[r + b];
        o0s[k1] = a;
        l1 = off[r + b + 1] - a;
    }
    unsigned pr = l0 + l1;
    unsigned incl = pr;
#pragma unroll
    for (int o = 1; o < 64; o <<= 1) {
        unsigned x = __shfl_up(incl, o);
        if (lane >= o) incl += x;
    }
    if (lane == 63) wsum[wave] = incl;
    __syncthreads();
    unsigned wbase = 0;
#pragma unroll
    for (int w = 0; w < R_THREADS / 64; ++w)
        wbase += (w < wave) ? wsum[w] : 0u;
    unsigned X = wbase + incl - pr;
    if (k0 < ntiles) cum[k0] = X;
    if (k1 < ntiles) cum[k1] = X + l0;
    if (tid == R_THREADS - 1) cum[ntiles] = wbase + incl;
    __syncthreads();
    unsigned T = cum[ntiles];

    float m0 = 0.f, m1 = 0.f, m2 = 0.f, m3 = 0.f, m4 = 0.f, m5 = 0.f,
          m6 = 0.f, m7 = 0.f, m8 = 0.f, m9 = 0.f, m10 = 0.f, m11 = 0.f,
          m12 = 0.f;

    for (unsigned tbase = 0; tbase < T; tbase += TILE) {
        cnt[tid] = 0;
        __syncthreads();                                    // B1

        float4 p0j[NT_R], p1j[NT_R];
        unsigned rankj[NT_R]; int lfj[NT_R]; bool actj[NT_R];
#pragma unroll
        for (int j = 0; j < NT_R; ++j) {
            unsigned g = tbase + (unsigned)tid + (unsigned)j * R_THREADS;
            actj[j] = (g < T);
            lfj[j] = 0; rankj[j] = 0;
            if (actj[j]) {
                int lo = 0, hi = ntiles - 1;
                while (lo < hi) {                  // LDS binary search
                    int mid = (lo + hi + 1) >> 1;
                    if (cum[mid] <= g) lo = mid; else hi = mid - 1;
                }
                size_t idx = (size_t)lo * TILE_B + o0s[lo] + (g - cum[lo]);
                const float4* p = (const float4*)(payload + idx * 8);
                p0j[j] = p[0];
                p1j[j] = p[1];
                lfj[j] = __float_as_int(p0j[j].w) & (BFRAGS - 1);
                rankj[j] = atomicAdd(&cnt[lfj[j]], 1u);
            }
        }
        __syncthreads();                                    // B2

        unsigned v = cnt[tid];
        unsigned incl2 = v;
#pragma unroll
        for (int o = 1; o < 64; o <<= 1) {
            unsigned x = __shfl_up(incl2, o);
            if (lane >= o) incl2 += x;
        }
        if (lane == 63) wsum[wave] = incl2;
        __syncthreads();                                    // S1
        unsigned wb2 = 0;
#pragma unroll
        for (int w = 0; w < R_THREADS / 64; ++w)
            wb2 += (w < wave) ? wsum[w] : 0u;
        fstart[tid] = wb2 + incl2 - v;
        if (tid == R_THREADS - 1) fstart[BFRAGS] = wb2 + incl2;
        __syncthreads();                                    // S2

#pragma unroll
        for (int j = 0; j < NT_R; ++j) {
            if (actj[j]) {
                unsigned slot = fstart[lfj[j]] + rankj[j];
                float4* d = (float4*)&stage[(size_t)slot * 8];
                d[0] = p0j[j];
                d[1] = p1j[j];
            }
        }
        __syncthreads();                                    // B3

        unsigned e0 = fstart[tid], e1 = fstart[tid + 1];
        for (unsigned u = e0; u < e1; ++u) {
            const float4* q = (const float4*)&stage[(size_t)u * 8];
            float4 a = q[0];
            float4 c = q[1];
            float fx = a.x, fy = a.y, fz = a.z;
            float rx = c.x, ry = c.y, rz = c.z;
            m0 += 1.0f;
            m1 += fx; m2 += fy; m3 += fz;
            m4 += ry * fz - rz * fy;
            m5 += rz * fx - rx * fz;
            m6 += rx * fy - ry * fx;
            m7 += rx * rx; m8 += ry * ry; m9 += rz * rz;
            m10 += rx * ry; m11 += rx * rz; m12 += ry * rz;
        }
        __syncthreads();
    }

    int fid = (b << BSHIFT) + tid;
    if (fid < n_frag) {
        float sv[NACC] = {m0, m1, m2, m3, m4, m5, m6,
                          m7, m8, m9, m10, m11, m12};
        float v[3], o[3];
        solve_frag(sv, frag_sizes[fid], v, o);
        out[3 * fid + 0] = v[0];
        out[3 * fid + 1] = v[1];
        out[3 * fid + 2] = v[2];
        float* om = out + 3 * (size_t)n_frag;
        om[3 * fid + 0] = o[0];
        om[3 * fid + 1] = o[1];
        om[3 * fid + 2] = o[2];
    }
}

// ---------------------------------------------------------------------------

static inline size_t pad256(size_t x) { return (x + 255) & ~(size_t)255; }

extern "C" void kernel_launch(void* const* d_in, const int* in_sizes, int n_in,
                              void* d_out, int out_size, void* d_ws, size_t ws_size,
                              hipStream_t stream) {
    const float* f_atom   = (const float*)d_in[0];
    const float* atom_pos = (const float*)d_in[1];
    const float* T_frag   = (const float*)d_in[2];
    const int*   frag_id  = (const int*)d_in[3];
    const int*   frag_sizes = (const int*)d_in[5];

    int n_atom = in_sizes[0] / 3;
    int n_frag = in_sizes[2] / 3;
    int nb     = (n_frag + BFRAGS - 1) >> BSHIFT;
    int ntiles = (n_atom + TILE_B - 1) / TILE_B;

    size_t off_bytes = pad256((size_t)ntiles * (nb + 1) * sizeof(unsigned));
    size_t payload_bytes = (size_t)ntiles * TILE_B * 8 * sizeof(float);
    bool sorted_ok = (nb <= NBMAX) && (ntiles <= MAXTILES) &&
                     (off_bytes + payload_bytes <= ws_size);

    if (sorted_ok) {
        unsigned* off  = (unsigned*)d_ws;
        float* payload = (float*)((char*)d_ws + off_bytes);

        build_kernel<<<ntiles, B_THREADS, 0, stream>>>(
            f_atom, atom_pos, T_frag, frag_id, off, payload, n_atom, nb);
        reduce_kernel<<<nb, R_THREADS, 0, stream>>>(
            payload, off, frag_sizes, (float*)d_out, n_frag, nb, ntiles);
    } else {
        float* acc = (float*)d_ws;
        hipMemsetAsync(acc, 0, (size_t)NACC * n_frag * sizeof(float), stream);
        int threads = 256;
        atom_accum_kernel<<<(n_atom + threads - 1) / threads, threads, 0, stream>>>(
            f_atom, atom_pos, T_frag, frag_id, acc, n_atom, n_frag);
        finalize_accum_kernel<<<(n_frag + threads - 1) / threads, threads, 0, stream>>>(
            acc, frag_sizes, (float*)d_out, n_frag);
    }
}

// Round 17
// 99.849 us; speedup vs baseline: 1.0317x; 1.0317x over previous
//
#include <hip/hip_runtime.h>

// ---------------------------------------------------------------------------
// Counting-sort to a globally bucket-sorted payload + tiled zero-float-atomic
// reduction. Round-17 = r14 (best measured: 84.5us) + ONE change (r16 fixed):
//   * payload write-out uses __builtin_nontemporal_store via native clang
//     ext_vector_type(4) (HIP float4* is rejected by the builtin): bypass L2
//     so HBM sees the staged LINEAR slot walk (sequential ~335B runs) instead
//     of pseudo-LRU random 64B dirty-line evictions (r15 evidence: 35MB of
//     build's writes still draining in the following kernel's window).
// Fallback (ws too small / nb > 512): round-1 device-scope atomics.
// ---------------------------------------------------------------------------

#define BSHIFT 9
#define BFRAGS (1 << BSHIFT)     // 512 fragments per bucket
#define NBMAX  512               // max buckets on sorted path
#define NACC   13

#define B_THREADS 1024
#define TILE_B    2048           // build tile; stage = 64 KB
#define NT_B      2              // slots per thread (TILE_B / B_THREADS)
#define CHUNK     (TILE_B * 2)   // 4096 atoms per hist/build block
#define R_THREADS 512
#define TILE      1024           // reduce tile; stage = 32 KB
#define CS_PER_LANE 8            // colscan: chunks per lane (nreg <= 512)

typedef float nvf4 __attribute__((ext_vector_type(4)));  // nt-store-compatible

// ---------------- fallback path (round-1, known correct) -------------------
__global__ void atom_accum_kernel(const float* __restrict__ f_atom,
                                  const float* __restrict__ atom_pos,
                                  const float* __restrict__ T_frag,
                                  const int*   __restrict__ frag_id,
                                  float* __restrict__ acc,
                                  int n_atom, int n_frag) {
    int i = blockIdx.x * blockDim.x + threadIdx.x;
    if (i >= n_atom) return;
    float fx = f_atom[3 * i + 0], fy = f_atom[3 * i + 1], fz = f_atom[3 * i + 2];
    float px = atom_pos[3 * i + 0], py = atom_pos[3 * i + 1], pz = atom_pos[3 * i + 2];
    int fid = frag_id[i];
    float rx = px - T_frag[3 * fid + 0];
    float ry = py - T_frag[3 * fid + 1];
    float rz = pz - T_frag[3 * fid + 2];
    atomicAdd(&acc[0 * n_frag + fid], 1.0f);
    atomicAdd(&acc[1 * n_frag + fid], fx);
    atomicAdd(&acc[2 * n_frag + fid], fy);
    atomicAdd(&acc[3 * n_frag + fid], fz);
    atomicAdd(&acc[4 * n_frag + fid], ry * fz - rz * fy);
    atomicAdd(&acc[5 * n_frag + fid], rz * fx - rx * fz);
    atomicAdd(&acc[6 * n_frag + fid], rx * fy - ry * fx);
    atomicAdd(&acc[7 * n_frag + fid], rx * rx);
    atomicAdd(&acc[8 * n_frag + fid], ry * ry);
    atomicAdd(&acc[9 * n_frag + fid], rz * rz);
    atomicAdd(&acc[10 * n_frag + fid], rx * ry);
    atomicAdd(&acc[11 * n_frag + fid], rx * rz);
    atomicAdd(&acc[12 * n_frag + fid], ry * rz);
}

__device__ __forceinline__ void solve_frag(const float s[NACC], int fs,
                                           float* vout, float* oout) {
    float inv_cnt = 1.0f / fmaxf(s[0], 1.0f);
    vout[0] = s[1] * inv_cnt;
    vout[1] = s[2] * inv_cnt;
    vout[2] = s[3] * inv_cnt;

    double sxx = (double)s[7], syy = (double)s[8], szz = (double)s[9];
    double sxy = (double)s[10], sxz = (double)s[11], syz = (double)s[12];
    const double eps = 1e-4;
    double d = sxx + syy + szz;
    double a00 = d - sxx + eps, a11 = d - syy + eps, a22 = d - szz + eps;
    double a01 = -sxy, a02 = -sxz, a12 = -syz;

    double c00 = a11 * a22 - a12 * a12;
    double c01 = a02 * a12 - a01 * a22;
    double c02 = a01 * a12 - a02 * a11;
    double det = a00 * c00 + a01 * c01 + a02 * c02;
    double inv_det = (det != 0.0) ? 1.0 / det : 0.0;
    double c11 = a00 * a22 - a02 * a02;
    double c12 = a01 * a02 - a00 * a12;
    double c22 = a00 * a11 - a01 * a01;

    double tx = (double)s[4], ty = (double)s[5], tz = (double)s[6];
    if (fs <= 1) {
        oout[0] = 0.0f; oout[1] = 0.0f; oout[2] = 0.0f;
    } else {
        oout[0] = (float)((c00 * tx + c01 * ty + c02 * tz) * inv_det);
        oout[1] = (float)((c01 * tx + c11 * ty + c12 * tz) * inv_det);
        oout[2] = (float)((c02 * tx + c12 * ty + c22 * tz) * inv_det);
    }
}

__global__ void finalize_accum_kernel(const float* __restrict__ acc,
                                      const int* __restrict__ frag_sizes,
                                      float* __restrict__ out, int n_frag) {
    int i = blockIdx.x * blockDim.x + threadIdx.x;
    if (i >= n_frag) return;
    float s[NACC];
#pragma unroll
    for (int c = 0; c < NACC; ++c) s[c] = acc[(size_t)c * n_frag + i];
    float v[3], o[3];
    solve_frag(s, frag_sizes[i], v, o);
    out[3 * i + 0] = v[0]; out[3 * i + 1] = v[1]; out[3 * i + 2] = v[2];
    float* om = out + 3 * (size_t)n_frag;
    om[3 * i + 0] = o[0]; om[3 * i + 1] = o[1]; om[3 * i + 2] = o[2];
}

// ---------------- sorted path ----------------------------------------------

// Bijective XCD-chunked swizzle: consecutive work chunks land on one XCD.
__device__ __forceinline__ int xcd_swizzle(int orig, int n) {
    int q = n >> 3, r = n & 7;
    int xcd = orig & 7, slot = orig >> 3;
    return (xcd < r ? xcd * (q + 1) : r * (q + 1) + (xcd - r) * q) + slot;
}

__global__ __launch_bounds__(B_THREADS)
void hist_kernel(const int* __restrict__ frag_id, unsigned* __restrict__ h,
                 int n_atom, int nb) {
    __shared__ unsigned hh[NBMAX];
    int tid = threadIdx.x;
    if (tid < NBMAX) hh[tid] = 0;
    __syncthreads();
    int c0 = blockIdx.x * CHUNK;
    int cend = min(c0 + CHUNK, n_atom);
    for (int i = c0 + tid; i < cend; i += B_THREADS)
        atomicAdd(&hh[frag_id[i] >> BSHIFT], 1u);
    __syncthreads();
    size_t row = (size_t)blockIdx.x * nb;
    if (tid < nb) h[row + tid] = hh[tid];
}

// One wave per bucket; lane l owns chunks [8l, 8l+8): one pipelined load
// round + in-register scan + wave shuffle-scan of lane sums. nreg <= 512.
__global__ void colscan_kernel(unsigned* __restrict__ h, unsigned* __restrict__ T,
                               int nb, int nreg) {
    int wid = (blockIdx.x * blockDim.x + threadIdx.x) >> 6;
    int lane = threadIdx.x & 63;
    if (wid >= nb) return;
    unsigned v[CS_PER_LANE];
    int base = lane * CS_PER_LANE;
#pragma unroll
    for (int j = 0; j < CS_PER_LANE; ++j) {
        int k = base + j;
        v[j] = (k < nreg) ? h[(size_t)k * nb + wid] : 0u;
    }
    unsigned sum = 0;
#pragma unroll
    for (int j = 0; j < CS_PER_LANE; ++j) {
        unsigned t = v[j]; v[j] = sum; sum += t;   // in-lane exclusive
    }
    unsigned incl = sum;
#pragma unroll
    for (int o = 1; o < 64; o <<= 1) {
        unsigned x = __shfl_up(incl, o);
        if (lane >= o) incl += x;
    }
    unsigned lanebase = incl - sum;
#pragma unroll
    for (int j = 0; j < CS_PER_LANE; ++j) {
        int k = base + j;
        if (k < nreg) h[(size_t)k * nb + wid] = lanebase + v[j];
    }
    if (lane == 63) T[wid] = incl;
}

// Single wave, 8 values/lane in-register exclusive scan. nb <= 512.
__global__ void gscan_kernel(const unsigned* __restrict__ T,
                             unsigned* __restrict__ gstart, int nb) {
    int lane = threadIdx.x;
    unsigned v[8];
    int base = lane * 8;
#pragma unroll
    for (int j = 0; j < 8; ++j) v[j] = (base + j < nb) ? T[base + j] : 0u;
    unsigned sum = 0;
#pragma unroll
    for (int j = 0; j < 8; ++j) {
        unsigned t = v[j]; v[j] = sum; sum += t;
    }
    unsigned incl = sum;
#pragma unroll
    for (int o = 1; o < 64; o <<= 1) {
        unsigned x = __shfl_up(incl, o);
        if (lane >= o) incl += x;
    }
    unsigned lanebase = incl - sum;
#pragma unroll
    for (int j = 0; j < 8; ++j)
        if (base + j < nb) gstart[base + j] = lanebase + v[j];
    if (lane == 63) gstart[nb] = incl;
}

__global__ __launch_bounds__(B_THREADS)
void build_kernel(const float* __restrict__ f_atom,
                  const float* __restrict__ atom_pos,
                  const float* __restrict__ T_frag,
                  const int* __restrict__ frag_id,
                  const unsigned* __restrict__ h,
                  const unsigned* __restrict__ gstart,
                  float* __restrict__ payload,
                  int n_atom, int nb, int nreg) {
    __shared__ float stage[TILE_B * 8];        // 64 KB bucket-sorted tile
    __shared__ unsigned cursor[NBMAX];         // global write cursor per bucket
    __shared__ unsigned cnt[NBMAX];
    __shared__ unsigned tfs[NBMAX];            // tile-local exclusive starts
    __shared__ unsigned wsum[B_THREADS / 64];  // 16

    int tid = threadIdx.x;
    int wave = tid >> 6, lane = tid & 63;
    int blk = xcd_swizzle(blockIdx.x, nreg);   // chunk index, XCD-contiguous

    size_t row = (size_t)blk * nb;
    if (tid < nb) cursor[tid] = gstart[tid] + h[row + tid];

    int c0 = blk * CHUNK;
    int cend = min(c0 + CHUNK, n_atom);

    for (int tbase = c0; tbase < cend; tbase += TILE_B) {
        int tcount = min(TILE_B, cend - tbase);
        if (tid < NBMAX) cnt[tid] = 0;
        __syncthreads();                                    // B1

        // load + rank + dst (cursor stable during tile)
        float4 p0j[NT_B], p1j[NT_B];
        unsigned rankj[NT_B]; int bj[NT_B]; bool actj[NT_B];
#pragma unroll
        for (int j = 0; j < NT_B; ++j) {
            int i = tbase + tid + j * B_THREADS;
            actj[j] = (i < cend);
            bj[j] = 0; rankj[j] = 0;
            if (actj[j]) {
                int fid = frag_id[i];
                int b = fid >> BSHIFT;
                bj[j] = b;
                rankj[j] = atomicAdd(&cnt[b], 1u);
                float fx = f_atom[3 * i + 0], fy = f_atom[3 * i + 1],
                      fz = f_atom[3 * i + 2];
                float rx = atom_pos[3 * i + 0] - T_frag[3 * fid + 0];
                float ry = atom_pos[3 * i + 1] - T_frag[3 * fid + 1];
                float rz = atom_pos[3 * i + 2] - T_frag[3 * fid + 2];
                unsigned dst = cursor[b] + rankj[j];
                p0j[j] = make_float4(fx, fy, fz, __int_as_float(fid));
                p1j[j] = make_float4(rx, ry, rz, __uint_as_float(dst));
            }
        }
        __syncthreads();                                    // B2

        // barrier-uniform hierarchical scan of cnt[0..NBMAX)
        unsigned v = (tid < NBMAX) ? cnt[tid] : 0u;
        unsigned incl = v;
#pragma unroll
        for (int o = 1; o < 64; o <<= 1) {
            unsigned x = __shfl_up(incl, o);
            if (lane >= o) incl += x;
        }
        if (lane == 63) wsum[wave] = incl;
        __syncthreads();                                    // S1
        unsigned wbase = 0;
#pragma unroll
        for (int w = 0; w < B_THREADS / 64; ++w)
            wbase += (w < wave) ? wsum[w] : 0u;
        if (tid < NBMAX) tfs[tid] = wbase + incl - v;
        __syncthreads();                                    // S2

        // stage bucket-sorted (dst already packed in p1.w)
#pragma unroll
        for (int j = 0; j < NT_B; ++j) {
            if (actj[j]) {
                unsigned slot = tfs[bj[j]] + rankj[j];
                float4* d = (float4*)&stage[(size_t)slot * 8];
                d[0] = p0j[j];
                d[1] = p1j[j];
            }
        }
        __syncthreads();                                    // B3

        // write-out: consecutive slots -> consecutive dst within bucket runs.
        // NON-TEMPORAL (native ext_vector_type for the builtin): bypass L2 so
        // HBM sees issue order (sequential runs), not pseudo-LRU random 64B
        // dirty-line evictions.
        for (int s = tid; s < tcount; s += B_THREADS) {
            const nvf4* q = (const nvf4*)&stage[(size_t)s * 8];
            nvf4 a = q[0];
            nvf4 c = q[1];
            unsigned dst = __float_as_uint(c.w);
            nvf4* p = (nvf4*)(payload + (size_t)dst * 8);
            __builtin_nontemporal_store(a, &p[0]);
            __builtin_nontemporal_store(c, &p[1]);
        }
        // advance own cursor (cnt[tid] valid until next B1 reset)
        if (tid < nb) cursor[tid] += cnt[tid];
    }
}

__global__ __launch_bounds__(R_THREADS)
void reduce_kernel(const float* __restrict__ payload,
                   const unsigned* __restrict__ gstart,
                   const int* __restrict__ frag_sizes,
                   float* __restrict__ out, int n_frag, int nb) {
    __shared__ float stage[TILE * 8];         // 32 KB fragment-sorted tile
    __shared__ unsigned cnt[BFRAGS];
    __shared__ unsigned fstart[BFRAGS + 1];
    __shared__ unsigned wsum[R_THREADS / 64];

    int b = xcd_swizzle(blockIdx.x, nb);      // bucket, XCD-contiguous ranges
    int tid = threadIdx.x;                    // 0..511; thread t owns frag t
    int wave = tid >> 6, lane = tid & 63;
    unsigned s0 = gstart[b], s1 = gstart[b + 1];

    float m0 = 0.f, m1 = 0.f, m2 = 0.f, m3 = 0.f, m4 = 0.f, m5 = 0.f,
          m6 = 0.f, m7 = 0.f, m8 = 0.f, m9 = 0.f, m10 = 0.f, m11 = 0.f,
          m12 = 0.f;

    for (unsigned tbase = s0; tbase < s1; tbase += TILE) {
        cnt[tid] = 0;
        __syncthreads();                                    // B1

        float4 p0j[2], p1j[2];
        unsigned rankj[2]; int lfj[2]; bool actj[2];
#pragma unroll
        for (int j = 0; j < 2; ++j) {
            unsigned s = tbase + (unsigned)tid + (unsigned)j * R_THREADS;
            actj[j] = (s < s1);
            lfj[j] = 0; rankj[j] = 0;
            if (actj[j]) {
                const float4* p = (const float4*)(payload + (size_t)s * 8);
                p0j[j] = p[0];
                p1j[j] = p[1];
                lfj[j] = __float_as_int(p0j[j].w) & (BFRAGS - 1);
                rankj[j] = atomicAdd(&cnt[lfj[j]], 1u);
            }
        }
        __syncthreads();                                    // B2

        unsigned v = cnt[tid];
        unsigned incl = v;
#pragma unroll
        for (int o = 1; o < 64; o <<= 1) {
            unsigned x = __shfl_up(incl, o);
            if (lane >= o) incl += x;
        }
        if (lane == 63) wsum[wave] = incl;
        __syncthreads();                                    // S1
        unsigned wbase = 0;
#pragma unroll
        for (int w = 0; w < R_THREADS / 64; ++w)
            wbase += (w < wave) ? wsum[w] : 0u;
        fstart[tid] = wbase + incl - v;
        if (tid == R_THREADS - 1) fstart[BFRAGS] = wbase + incl;
        __syncthreads();                                    // S2

#pragma unroll
        for (int j = 0; j < 2; ++j) {
            if (actj[j]) {
                unsigned slot = fstart[lfj[j]] + rankj[j];
                float4* d = (float4*)&stage[(size_t)slot * 8];
                d[0] = p0j[j];
                d[1] = p1j[j];
            }
        }
        __syncthreads();                                    // B3

        unsigned e0 = fstart[tid], e1 = fstart[tid + 1];
        for (unsigned u = e0; u < e1; ++u) {
            const float4* q = (const float4*)&stage[(size_t)u * 8];
            float4 a = q[0];
            float4 c = q[1];
            float fx = a.x, fy = a.y, fz = a.z;
            float rx = c.x, ry = c.y, rz = c.z;
            m0 += 1.0f;
            m1 += fx; m2 += fy; m3 += fz;
            m4 += ry * fz - rz * fy;
            m5 += rz * fx - rx * fz;
            m6 += rx * fy - ry * fx;
            m7 += rx * rx; m8 += ry * ry; m9 += rz * rz;
            m10 += rx * ry; m11 += rx * rz; m12 += ry * rz;
        }
        __syncthreads();
    }

    int fid = (b << BSHIFT) + tid;
    if (fid < n_frag) {
        float sv[NACC] = {m0, m1, m2, m3, m4, m5, m6,
                          m7, m8, m9, m10, m11, m12};
        float v[3], o[3];
        solve_frag(sv, frag_sizes[fid], v, o);
        out[3 * fid + 0] = v[0];
        out[3 * fid + 1] = v[1];
        out[3 * fid + 2] = v[2];
        float* om = out + 3 * (size_t)n_frag;
        om[3 * fid + 0] = o[0];
        om[3 * fid + 1] = o[1];
        om[3 * fid + 2] = o[2];
    }
}

// ---------------------------------------------------------------------------

static inline size_t pad256(size_t x) { return (x + 255) & ~(size_t)255; }

extern "C" void kernel_launch(void* const* d_in, const int* in_sizes, int n_in,
                              void* d_out, int out_size, void* d_ws, size_t ws_size,
                              hipStream_t stream) {
    const float* f_atom   = (const float*)d_in[0];
    const float* atom_pos = (const float*)d_in[1];
    const float* T_frag   = (const float*)d_in[2];
    const int*   frag_id  = (const int*)d_in[3];
    const int*   frag_sizes = (const int*)d_in[5];

    int n_atom = in_sizes[0] / 3;
    int n_frag = in_sizes[2] / 3;
    int nb   = (n_frag + BFRAGS - 1) >> BSHIFT;
    int nreg = (n_atom + CHUNK - 1) / CHUNK;

    size_t h_bytes   = pad256((size_t)nreg * nb * sizeof(unsigned));
    size_t ctl_bytes = pad256(((size_t)nb + (size_t)nb + 1) * sizeof(unsigned));
    size_t payload_bytes = (size_t)n_atom * 8 * sizeof(float);
    bool sorted_ok = (nb <= NBMAX) && (nreg <= 64 * CS_PER_LANE) &&
                     (h_bytes + ctl_bytes + payload_bytes <= ws_size);

    if (sorted_ok) {
        unsigned* h      = (unsigned*)d_ws;
        unsigned* T      = (unsigned*)((char*)d_ws + h_bytes);
        unsigned* gstart = T + nb;
        float* payload   = (float*)((char*)d_ws + h_bytes + ctl_bytes);

        hist_kernel<<<nreg, B_THREADS, 0, stream>>>(frag_id, h, n_atom, nb);
        int cs_blocks = (nb * 64 + 255) / 256;
        colscan_kernel<<<cs_blocks, 256, 0, stream>>>(h, T, nb, nreg);
        gscan_kernel<<<1, 64, 0, stream>>>(T, gstart, nb);
        build_kernel<<<nreg, B_THREADS, 0, stream>>>(f_atom, atom_pos, T_frag,
                                                     frag_id, h, gstart, payload,
                                                     n_atom, nb, nreg);
        reduce_kernel<<<nb, R_THREADS, 0, stream>>>(payload, gstart, frag_sizes,
                                                    (float*)d_out, n_frag, nb);
    } else {
        float* acc = (float*)d_ws;
        hipMemsetAsync(acc, 0, (size_t)NACC * n_frag * sizeof(float), stream);
        int threads = 256;
        atom_accum_kernel<<<(n_atom + threads - 1) / threads, threads, 0, stream>>>(
            f_atom, atom_pos, T_frag, frag_id, acc, n_atom, n_frag);
        finalize_accum_kernel<<<(n_frag + threads - 1) / threads, threads, 0, stream>>>(
            acc, frag_sizes, (float*)d_out, n_frag);
    }
}

// Round 18
// 83.919 us; speedup vs baseline: 1.2275x; 1.1898x over previous
//
#include <hip/hip_runtime.h>

// ---------------------------------------------------------------------------
// FINAL: counting-sort to a globally bucket-sorted payload + tiled
// zero-float-atomic reduction. This is r14 verbatim (best measured: 84.5us).
// r17's NT-store A/B falsified the last open theory (L2-eviction-order):
// the scatter step is transaction-count-bound (~2M scattered 32B records,
// order-independent) -- structural floor for this op shape:
//   build ~55us + reduce ~14us + hist ~5us + control/launch ~10us.
// Levers tested & exhausted: run length (r12), occupancy (r13), LDS-staged
// write coalescing (r10/11), NT stores (r17), read-side scatter (r15 worse),
// global atomics (r1/2: 15x slower), LDS float atomics (r7: 2x slower).
// Fallback (ws too small / nb > 512): round-1 device-scope atomics.
// ---------------------------------------------------------------------------

#define BSHIFT 9
#define BFRAGS (1 << BSHIFT)     // 512 fragments per bucket
#define NBMAX  512               // max buckets on sorted path
#define NACC   13

#define B_THREADS 1024
#define TILE_B    2048           // build tile; stage = 64 KB
#define NT_B      2              // slots per thread (TILE_B / B_THREADS)
#define CHUNK     (TILE_B * 2)   // 4096 atoms per hist/build block
#define R_THREADS 512
#define TILE      1024           // reduce tile; stage = 32 KB
#define CS_PER_LANE 8            // colscan: chunks per lane (nreg <= 512)

// ---------------- fallback path (round-1, known correct) -------------------
__global__ void atom_accum_kernel(const float* __restrict__ f_atom,
                                  const float* __restrict__ atom_pos,
                                  const float* __restrict__ T_frag,
                                  const int*   __restrict__ frag_id,
                                  float* __restrict__ acc,
                                  int n_atom, int n_frag) {
    int i = blockIdx.x * blockDim.x + threadIdx.x;
    if (i >= n_atom) return;
    float fx = f_atom[3 * i + 0], fy = f_atom[3 * i + 1], fz = f_atom[3 * i + 2];
    float px = atom_pos[3 * i + 0], py = atom_pos[3 * i + 1], pz = atom_pos[3 * i + 2];
    int fid = frag_id[i];
    float rx = px - T_frag[3 * fid + 0];
    float ry = py - T_frag[3 * fid + 1];
    float rz = pz - T_frag[3 * fid + 2];
    atomicAdd(&acc[0 * n_frag + fid], 1.0f);
    atomicAdd(&acc[1 * n_frag + fid], fx);
    atomicAdd(&acc[2 * n_frag + fid], fy);
    atomicAdd(&acc[3 * n_frag + fid], fz);
    atomicAdd(&acc[4 * n_frag + fid], ry * fz - rz * fy);
    atomicAdd(&acc[5 * n_frag + fid], rz * fx - rx * fz);
    atomicAdd(&acc[6 * n_frag + fid], rx * fy - ry * fx);
    atomicAdd(&acc[7 * n_frag + fid], rx * rx);
    atomicAdd(&acc[8 * n_frag + fid], ry * ry);
    atomicAdd(&acc[9 * n_frag + fid], rz * rz);
    atomicAdd(&acc[10 * n_frag + fid], rx * ry);
    atomicAdd(&acc[11 * n_frag + fid], rx * rz);
    atomicAdd(&acc[12 * n_frag + fid], ry * rz);
}

__device__ __forceinline__ void solve_frag(const float s[NACC], int fs,
                                           float* vout, float* oout) {
    float inv_cnt = 1.0f / fmaxf(s[0], 1.0f);
    vout[0] = s[1] * inv_cnt;
    vout[1] = s[2] * inv_cnt;
    vout[2] = s[3] * inv_cnt;

    double sxx = (double)s[7], syy = (double)s[8], szz = (double)s[9];
    double sxy = (double)s[10], sxz = (double)s[11], syz = (double)s[12];
    const double eps = 1e-4;
    double d = sxx + syy + szz;
    double a00 = d - sxx + eps, a11 = d - syy + eps, a22 = d - szz + eps;
    double a01 = -sxy, a02 = -sxz, a12 = -syz;

    double c00 = a11 * a22 - a12 * a12;
    double c01 = a02 * a12 - a01 * a22;
    double c02 = a01 * a12 - a02 * a11;
    double det = a00 * c00 + a01 * c01 + a02 * c02;
    double inv_det = (det != 0.0) ? 1.0 / det : 0.0;
    double c11 = a00 * a22 - a02 * a02;
    double c12 = a01 * a02 - a00 * a12;
    double c22 = a00 * a11 - a01 * a01;

    double tx = (double)s[4], ty = (double)s[5], tz = (double)s[6];
    if (fs <= 1) {
        oout[0] = 0.0f; oout[1] = 0.0f; oout[2] = 0.0f;
    } else {
        oout[0] = (float)((c00 * tx + c01 * ty + c02 * tz) * inv_det);
        oout[1] = (float)((c01 * tx + c11 * ty + c12 * tz) * inv_det);
        oout[2] = (float)((c02 * tx + c12 * ty + c22 * tz) * inv_det);
    }
}

__global__ void finalize_accum_kernel(const float* __restrict__ acc,
                                      const int* __restrict__ frag_sizes,
                                      float* __restrict__ out, int n_frag) {
    int i = blockIdx.x * blockDim.x + threadIdx.x;
    if (i >= n_frag) return;
    float s[NACC];
#pragma unroll
    for (int c = 0; c < NACC; ++c) s[c] = acc[(size_t)c * n_frag + i];
    float v[3], o[3];
    solve_frag(s, frag_sizes[i], v, o);
    out[3 * i + 0] = v[0]; out[3 * i + 1] = v[1]; out[3 * i + 2] = v[2];
    float* om = out + 3 * (size_t)n_frag;
    om[3 * i + 0] = o[0]; om[3 * i + 1] = o[1]; om[3 * i + 2] = o[2];
}

// ---------------- sorted path ----------------------------------------------

// Bijective XCD-chunked swizzle: consecutive work chunks land on one XCD.
__device__ __forceinline__ int xcd_swizzle(int orig, int n) {
    int q = n >> 3, r = n & 7;
    int xcd = orig & 7, slot = orig >> 3;
    return (xcd < r ? xcd * (q + 1) : r * (q + 1) + (xcd - r) * q) + slot;
}

__global__ __launch_bounds__(B_THREADS)
void hist_kernel(const int* __restrict__ frag_id, unsigned* __restrict__ h,
                 int n_atom, int nb) {
    __shared__ unsigned hh[NBMAX];
    int tid = threadIdx.x;
    if (tid < NBMAX) hh[tid] = 0;
    __syncthreads();
    int c0 = blockIdx.x * CHUNK;
    int cend = min(c0 + CHUNK, n_atom);
    for (int i = c0 + tid; i < cend; i += B_THREADS)
        atomicAdd(&hh[frag_id[i] >> BSHIFT], 1u);
    __syncthreads();
    size_t row = (size_t)blockIdx.x * nb;
    if (tid < nb) h[row + tid] = hh[tid];
}

// One wave per bucket; lane l owns chunks [8l, 8l+8): one pipelined load
// round + in-register scan + wave shuffle-scan of lane sums. nreg <= 512.
__global__ void colscan_kernel(unsigned* __restrict__ h, unsigned* __restrict__ T,
                               int nb, int nreg) {
    int wid = (blockIdx.x * blockDim.x + threadIdx.x) >> 6;
    int lane = threadIdx.x & 63;
    if (wid >= nb) return;
    unsigned v[CS_PER_LANE];
    int base = lane * CS_PER_LANE;
#pragma unroll
    for (int j = 0; j < CS_PER_LANE; ++j) {
        int k = base + j;
        v[j] = (k < nreg) ? h[(size_t)k * nb + wid] : 0u;
    }
    unsigned sum = 0;
#pragma unroll
    for (int j = 0; j < CS_PER_LANE; ++j) {
        unsigned t = v[j]; v[j] = sum; sum += t;   // in-lane exclusive
    }
    unsigned incl = sum;
#pragma unroll
    for (int o = 1; o < 64; o <<= 1) {
        unsigned x = __shfl_up(incl, o);
        if (lane >= o) incl += x;
    }
    unsigned lanebase = incl - sum;
#pragma unroll
    for (int j = 0; j < CS_PER_LANE; ++j) {
        int k = base + j;
        if (k < nreg) h[(size_t)k * nb + wid] = lanebase + v[j];
    }
    if (lane == 63) T[wid] = incl;
}

// Single wave, 8 values/lane in-register exclusive scan. nb <= 512.
__global__ void gscan_kernel(const unsigned* __restrict__ T,
                             unsigned* __restrict__ gstart, int nb) {
    int lane = threadIdx.x;
    unsigned v[8];
    int base = lane * 8;
#pragma unroll
    for (int j = 0; j < 8; ++j) v[j] = (base + j < nb) ? T[base + j] : 0u;
    unsigned sum = 0;
#pragma unroll
    for (int j = 0; j < 8; ++j) {
        unsigned t = v[j]; v[j] = sum; sum += t;
    }
    unsigned incl = sum;
#pragma unroll
    for (int o = 1; o < 64; o <<= 1) {
        unsigned x = __shfl_up(incl, o);
        if (lane >= o) incl += x;
    }
    unsigned lanebase = incl - sum;
#pragma unroll
    for (int j = 0; j < 8; ++j)
        if (base + j < nb) gstart[base + j] = lanebase + v[j];
    if (lane == 63) gstart[nb] = incl;
}

__global__ __launch_bounds__(B_THREADS)
void build_kernel(const float* __restrict__ f_atom,
                  const float* __restrict__ atom_pos,
                  const float* __restrict__ T_frag,
                  const int* __restrict__ frag_id,
                  const unsigned* __restrict__ h,
                  const unsigned* __restrict__ gstart,
                  float* __restrict__ payload,
                  int n_atom, int nb, int nreg) {
    __shared__ float stage[TILE_B * 8];        // 64 KB bucket-sorted tile
    __shared__ unsigned cursor[NBMAX];         // global write cursor per bucket
    __shared__ unsigned cnt[NBMAX];
    __shared__ unsigned tfs[NBMAX];            // tile-local exclusive starts
    __shared__ unsigned wsum[B_THREADS / 64];  // 16

    int tid = threadIdx.x;
    int wave = tid >> 6, lane = tid & 63;
    int blk = xcd_swizzle(blockIdx.x, nreg);   // chunk index, XCD-contiguous

    size_t row = (size_t)blk * nb;
    if (tid < nb) cursor[tid] = gstart[tid] + h[row + tid];

    int c0 = blk * CHUNK;
    int cend = min(c0 + CHUNK, n_atom);

    for (int tbase = c0; tbase < cend; tbase += TILE_B) {
        int tcount = min(TILE_B, cend - tbase);
        if (tid < NBMAX) cnt[tid] = 0;
        __syncthreads();                                    // B1

        // load + rank + dst (cursor stable during tile)
        float4 p0j[NT_B], p1j[NT_B];
        unsigned rankj[NT_B]; int bj[NT_B]; bool actj[NT_B];
#pragma unroll
        for (int j = 0; j < NT_B; ++j) {
            int i = tbase + tid + j * B_THREADS;
            actj[j] = (i < cend);
            bj[j] = 0; rankj[j] = 0;
            if (actj[j]) {
                int fid = frag_id[i];
                int b = fid >> BSHIFT;
                bj[j] = b;
                rankj[j] = atomicAdd(&cnt[b], 1u);
                float fx = f_atom[3 * i + 0], fy = f_atom[3 * i + 1],
                      fz = f_atom[3 * i + 2];
                float rx = atom_pos[3 * i + 0] - T_frag[3 * fid + 0];
                float ry = atom_pos[3 * i + 1] - T_frag[3 * fid + 1];
                float rz = atom_pos[3 * i + 2] - T_frag[3 * fid + 2];
                unsigned dst = cursor[b] + rankj[j];
                p0j[j] = make_float4(fx, fy, fz, __int_as_float(fid));
                p1j[j] = make_float4(rx, ry, rz, __uint_as_float(dst));
            }
        }
        __syncthreads();                                    // B2

        // barrier-uniform hierarchical scan of cnt[0..NBMAX)
        unsigned v = (tid < NBMAX) ? cnt[tid] : 0u;
        unsigned incl = v;
#pragma unroll
        for (int o = 1; o < 64; o <<= 1) {
            unsigned x = __shfl_up(incl, o);
            if (lane >= o) incl += x;
        }
        if (lane == 63) wsum[wave] = incl;
        __syncthreads();                                    // S1
        unsigned wbase = 0;
#pragma unroll
        for (int w = 0; w < B_THREADS / 64; ++w)
            wbase += (w < wave) ? wsum[w] : 0u;
        if (tid < NBMAX) tfs[tid] = wbase + incl - v;
        __syncthreads();                                    // S2

        // stage bucket-sorted (dst already packed in p1.w)
#pragma unroll
        for (int j = 0; j < NT_B; ++j) {
            if (actj[j]) {
                unsigned slot = tfs[bj[j]] + rankj[j];
                float4* d = (float4*)&stage[(size_t)slot * 8];
                d[0] = p0j[j];
                d[1] = p1j[j];
            }
        }
        __syncthreads();                                    // B3

        // write-out: consecutive slots -> consecutive dst within bucket runs
        for (int s = tid; s < tcount; s += B_THREADS) {
            const float4* q = (const float4*)&stage[(size_t)s * 8];
            float4 a = q[0];
            float4 c = q[1];
            unsigned dst = __float_as_uint(c.w);
            float4* p = (float4*)(payload + (size_t)dst * 8);
            p[0] = a;
            p[1] = c;          // .w carries dst bits; reduce ignores it
        }
        // advance own cursor (cnt[tid] valid until next B1 reset)
        if (tid < nb) cursor[tid] += cnt[tid];
    }
}

__global__ __launch_bounds__(R_THREADS)
void reduce_kernel(const float* __restrict__ payload,
                   const unsigned* __restrict__ gstart,
                   const int* __restrict__ frag_sizes,
                   float* __restrict__ out, int n_frag, int nb) {
    __shared__ float stage[TILE * 8];         // 32 KB fragment-sorted tile
    __shared__ unsigned cnt[BFRAGS];
    __shared__ unsigned fstart[BFRAGS + 1];
    __shared__ unsigned wsum[R_THREADS / 64];

    int b = xcd_swizzle(blockIdx.x, nb);      // bucket, XCD-contiguous ranges
    int tid = threadIdx.x;                    // 0..511; thread t owns frag t
    int wave = tid >> 6, lane = tid & 63;
    unsigned s0 = gstart[b], s1 = gstart[b + 1];

    float m0 = 0.f, m1 = 0.f, m2 = 0.f, m3 = 0.f, m4 = 0.f, m5 = 0.f,
          m6 = 0.f, m7 = 0.f, m8 = 0.f, m9 = 0.f, m10 = 0.f, m11 = 0.f,
          m12 = 0.f;

    for (unsigned tbase = s0; tbase < s1; tbase += TILE) {
        cnt[tid] = 0;
        __syncthreads();                                    // B1

        float4 p0j[2], p1j[2];
        unsigned rankj[2]; int lfj[2]; bool actj[2];
#pragma unroll
        for (int j = 0; j < 2; ++j) {
            unsigned s = tbase + (unsigned)tid + (unsigned)j * R_THREADS;
            actj[j] = (s < s1);
            lfj[j] = 0; rankj[j] = 0;
            if (actj[j]) {
                const float4* p = (const float4*)(payload + (size_t)s * 8);
                p0j[j] = p[0];
                p1j[j] = p[1];
                lfj[j] = __float_as_int(p0j[j].w) & (BFRAGS - 1);
                rankj[j] = atomicAdd(&cnt[lfj[j]], 1u);
            }
        }
        __syncthreads();                                    // B2

        unsigned v = cnt[tid];
        unsigned incl = v;
#pragma unroll
        for (int o = 1; o < 64; o <<= 1) {
            unsigned x = __shfl_up(incl, o);
            if (lane >= o) incl += x;
        }
        if (lane == 63) wsum[wave] = incl;
        __syncthreads();                                    // S1
        unsigned wbase = 0;
#pragma unroll
        for (int w = 0; w < R_THREADS / 64; ++w)
            wbase += (w < wave) ? wsum[w] : 0u;
        fstart[tid] = wbase + incl - v;
        if (tid == R_THREADS - 1) fstart[BFRAGS] = wbase + incl;
        __syncthreads();                                    // S2

#pragma unroll
        for (int j = 0; j < 2; ++j) {
            if (actj[j]) {
                unsigned slot = fstart[lfj[j]] + rankj[j];
                float4* d = (float4*)&stage[(size_t)slot * 8];
                d[0] = p0j[j];
                d[1] = p1j[j];
            }
        }
        __syncthreads();                                    // B3

        unsigned e0 = fstart[tid], e1 = fstart[tid + 1];
        for (unsigned u = e0; u < e1; ++u) {
            const float4* q = (const float4*)&stage[(size_t)u * 8];
            float4 a = q[0];
            float4 c = q[1];
            float fx = a.x, fy = a.y, fz = a.z;
            float rx = c.x, ry = c.y, rz = c.z;
            m0 += 1.0f;
            m1 += fx; m2 += fy; m3 += fz;
            m4 += ry * fz - rz * fy;
            m5 += rz * fx - rx * fz;
            m6 += rx * fy - ry * fx;
            m7 += rx * rx; m8 += ry * ry; m9 += rz * rz;
            m10 += rx * ry; m11 += rx * rz; m12 += ry * rz;
        }
        __syncthreads();
    }

    int fid = (b << BSHIFT) + tid;
    if (fid < n_frag) {
        float sv[NACC] = {m0, m1, m2, m3, m4, m5, m6,
                          m7, m8, m9, m10, m11, m12};
        float v[3], o[3];
        solve_frag(sv, frag_sizes[fid], v, o);
        out[3 * fid + 0] = v[0];
        out[3 * fid + 1] = v[1];
        out[3 * fid + 2] = v[2];
        float* om = out + 3 * (size_t)n_frag;
        om[3 * fid + 0] = o[0];
        om[3 * fid + 1] = o[1];
        om[3 * fid + 2] = o[2];
    }
}

// ---------------------------------------------------------------------------

static inline size_t pad256(size_t x) { return (x + 255) & ~(size_t)255; }

extern "C" void kernel_launch(void* const* d_in, const int* in_sizes, int n_in,
                              void* d_out, int out_size, void* d_ws, size_t ws_size,
                              hipStream_t stream) {
    const float* f_atom   = (const float*)d_in[0];
    const float* atom_pos = (const float*)d_in[1];
    const float* T_frag   = (const float*)d_in[2];
    const int*   frag_id  = (const int*)d_in[3];
    const int*   frag_sizes = (const int*)d_in[5];

    int n_atom = in_sizes[0] / 3;
    int n_frag = in_sizes[2] / 3;
    int nb   = (n_frag + BFRAGS - 1) >> BSHIFT;
    int nreg = (n_atom + CHUNK - 1) / CHUNK;

    size_t h_bytes   = pad256((size_t)nreg * nb * sizeof(unsigned));
    size_t ctl_bytes = pad256(((size_t)nb + (size_t)nb + 1) * sizeof(unsigned));
    size_t payload_bytes = (size_t)n_atom * 8 * sizeof(float);
    bool sorted_ok = (nb <= NBMAX) && (nreg <= 64 * CS_PER_LANE) &&
                     (h_bytes + ctl_bytes + payload_bytes <= ws_size);

    if (sorted_ok) {
        unsigned* h      = (unsigned*)d_ws;
        unsigned* T      = (unsigned*)((char*)d_ws + h_bytes);
        unsigned* gstart = T + nb;
        float* payload   = (float*)((char*)d_ws + h_bytes + ctl_bytes);

        hist_kernel<<<nreg, B_THREADS, 0, stream>>>(frag_id, h, n_atom, nb);
        int cs_blocks = (nb * 64 + 255) / 256;
        colscan_kernel<<<cs_blocks, 256, 0, stream>>>(h, T, nb, nreg);
        gscan_kernel<<<1, 64, 0, stream>>>(T, gstart, nb);
        build_kernel<<<nreg, B_THREADS, 0, stream>>>(f_atom, atom_pos, T_frag,
                                                     frag_id, h, gstart, payload,
                                                     n_atom, nb, nreg);
        reduce_kernel<<<nb, R_THREADS, 0, stream>>>(payload, gstart, frag_sizes,
                                                    (float*)d_out, n_frag, nb);
    } else {
        float* acc = (float*)d_ws;
        hipMemsetAsync(acc, 0, (size_t)NACC * n_frag * sizeof(float), stream);
        int threads = 256;
        atom_accum_kernel<<<(n_atom + threads - 1) / threads, threads, 0, stream>>>(
            f_atom, atom_pos, T_frag, frag_id, acc, n_atom, n_frag);
        finalize_accum_kernel<<<(n_frag + threads - 1) / threads, threads, 0, stream>>>(
            acc, frag_sizes, (float*)d_out, n_frag);
    }
}